// Round 1
// baseline (3100.478 us; speedup 1.0000x reference)
//
#include <hip/hip_runtime.h>
#include <cstdint>
#include <cstddef>

#define R_ 64
#define K_ 81
#define CF_ 256
#define NPTS_ 784
#define CIN_ 337

// ---------------- transpose feat [C][H][W] -> [H][W][C] ----------------
__global__ __launch_bounds__(256) void transpose_feat_kernel(const float* __restrict__ in,
                                                             float* __restrict__ out) {
  __shared__ float tile[32][33];
  int y = blockIdx.z;
  int x0 = blockIdx.x * 32, c0 = blockIdx.y * 32;
  int tx = threadIdx.x, ty = threadIdx.y;
#pragma unroll
  for (int j = 0; j < 32; j += 8)
    tile[ty + j][tx] = in[(size_t)(c0 + ty + j) * 65536 + (size_t)y * 256 + x0 + tx];
  __syncthreads();
#pragma unroll
  for (int j = 0; j < 32; j += 8)
    out[((size_t)y * 256 + (x0 + ty + j)) * 256 + c0 + tx] = tile[tx][ty + j];
}

// ---------------- transpose coarse [R][K][49] -> [R][49][K] ----------------
__global__ void transpose_coarse_kernel(const float* __restrict__ in, float* __restrict__ out) {
  int t = blockIdx.x * 256 + threadIdx.x;
  if (t >= R_ * 49 * K_) return;
  int k = t % K_;
  int t2 = t / K_;
  int pos = t2 % 49;
  int r = t2 / 49;
  out[t] = in[((size_t)r * K_ + k) * 49 + pos];
}

// ---------------- 2x bilinear upsample (jax.image.resize linear semantics) ----------------
__global__ void upsample_kernel(const float* __restrict__ in, float* __restrict__ out,
                                int B, int Hin, int Win) {
  int Wout = 2 * Win, Hout = 2 * Hin;
  size_t total = (size_t)B * Hout * Wout;
  size_t t = (size_t)blockIdx.x * 256 + threadIdx.x;
  if (t >= total) return;
  int ox = (int)(t % Wout);
  size_t t2 = t / Wout;
  int oy = (int)(t2 % Hout);
  int b = (int)(t2 / Hout);
  float sx = 0.5f * (float)ox - 0.25f;
  float sy = 0.5f * (float)oy - 0.25f;
  int x0, x1;
  float wx1;
  if (sx < 0.f) { x0 = 0; x1 = 0; wx1 = 0.f; }
  else if (sx >= (float)(Win - 1)) { x0 = Win - 1; x1 = Win - 1; wx1 = 0.f; }
  else { x0 = (int)sx; x1 = x0 + 1; wx1 = sx - (float)x0; }
  float wx0 = 1.f - wx1;
  int y0, y1;
  float wy1;
  if (sy < 0.f) { y0 = 0; y1 = 0; wy1 = 0.f; }
  else if (sy >= (float)(Hin - 1)) { y0 = Hin - 1; y1 = Hin - 1; wy1 = 0.f; }
  else { y0 = (int)sy; y1 = y0 + 1; wy1 = sy - (float)y0; }
  float wy0 = 1.f - wy1;
  const float* p = in + (size_t)b * Hin * Win;
  float r0 = wx0 * p[(size_t)y0 * Win + x0] + wx1 * p[(size_t)y0 * Win + x1];
  float r1 = wx0 * p[(size_t)y1 * Win + x0] + wx1 * p[(size_t)y1 * Win + x1];
  out[t] = wy0 * r0 + wy1 * r1;
}

// ---------------- iota selection (step 1: all 784 points) ----------------
__global__ void iota_kernel(int* __restrict__ sel) {
  int t = blockIdx.x * 256 + threadIdx.x;
  if (t < R_ * NPTS_) sel[t] = t % NPTS_;
}

// ---------------- per-ROI top-784 smallest |gt| (jax top_k tie semantics) ----------------
__global__ __launch_bounds__(256) void topk_kernel(const float* __restrict__ ml,
                                                   const int* __restrict__ labels,
                                                   int N, int* __restrict__ sel) {
  int r = blockIdx.x;
  const float* gt = ml + ((size_t)r * K_ + (labels[r] + 1)) * N;
  __shared__ unsigned int hist[256];
  __shared__ unsigned int sh_prefix, sh_remaining, sh_countless;
  int tid = threadIdx.x;

  unsigned int prefix = 0;
  unsigned int remaining = NPTS_;
  unsigned int count_less = 0;
  for (int pass = 0; pass < 4; ++pass) {
    int shift = 24 - 8 * pass;
    hist[tid] = 0;
    __syncthreads();
    for (int i = tid; i < N; i += 256) {
      unsigned int v = __float_as_uint(fabsf(gt[i]));
      bool match = (pass == 0) || ((v >> (shift + 8)) == prefix);
      if (match) atomicAdd(&hist[(v >> shift) & 255u], 1u);
    }
    __syncthreads();
    if (tid == 0) {
      unsigned int cum = 0, before = 0;
      int d = 255;
      for (int dd = 0; dd < 256; ++dd) {
        unsigned int c = hist[dd];
        if (cum + c >= remaining) { before = cum; d = dd; break; }
        cum += c;
      }
      sh_prefix = (prefix << 8) | (unsigned int)d;
      sh_remaining = remaining - before;
      sh_countless = count_less + before;
    }
    __syncthreads();
    prefix = sh_prefix;
    remaining = sh_remaining;
    count_less = sh_countless;
    __syncthreads();
  }
  unsigned int vstar = prefix;
  unsigned int need_eq = NPTS_ - count_less;

  // compaction: all <vstar, then first need_eq ==vstar by ascending index
  __shared__ unsigned int wtot_less[4], wtot_eq[4];
  unsigned int base_less = 0, base_eq = 0;
  int lane = tid & 63, wv = tid >> 6;
  int* selr = sel + (size_t)r * NPTS_;
  for (int base = 0; base < N; base += 256) {
    int i = base + tid;
    bool less = false, eq = false;
    if (i < N) {
      unsigned int v = __float_as_uint(fabsf(gt[i]));
      less = v < vstar;
      eq = v == vstar;
    }
    unsigned long long ml_ = __ballot(less);
    unsigned long long me_ = __ballot(eq);
    unsigned long long lanemask = (lane == 0) ? 0ull : ((~0ull) >> (64 - lane));
    unsigned int pl = __popcll(ml_ & lanemask);
    unsigned int pe = __popcll(me_ & lanemask);
    if (lane == 0) { wtot_less[wv] = (unsigned int)__popcll(ml_); wtot_eq[wv] = (unsigned int)__popcll(me_); }
    __syncthreads();
    unsigned int off_l = 0, off_e = 0, tot_l = 0, tot_e = 0;
#pragma unroll
    for (int w2 = 0; w2 < 4; ++w2) {
      unsigned int tl = wtot_less[w2], te = wtot_eq[w2];
      if (w2 < wv) { off_l += tl; off_e += te; }
      tot_l += tl;
      tot_e += te;
    }
    if (less) selr[base_less + off_l + pl] = i;
    if (eq) {
      unsigned int er = base_eq + off_e + pe;
      if (er < need_eq) selr[count_less + er] = i;
    }
    base_less += tot_l;
    base_eq += tot_e;
    __syncthreads();
  }
}

// ---------------- sample fine (feat HWC) + coarse (coarseT) into X0 [rp][337] ----------------
__global__ __launch_bounds__(256) void sample_kernel(const int* __restrict__ sel,
                                                     const float* __restrict__ bboxes,
                                                     const float* __restrict__ featT,
                                                     const float* __restrict__ coarseT,
                                                     float* __restrict__ X0,
                                                     int Wlev, int Hlev) {
  int rp = blockIdx.x;
  int r = rp / NPTS_;
  int idx = sel[rp];
  int tid = threadIdx.x;

  float px = ((float)(idx % Wlev) + 0.5f) / (float)Wlev;
  float py = ((float)(idx / Wlev) + 0.5f) / (float)Hlev;
  float bx0 = bboxes[r * 4 + 0], by0 = bboxes[r * 4 + 1];
  float bw = __fsub_rn(bboxes[r * 4 + 2], bx0);
  float bh = __fsub_rn(bboxes[r * 4 + 3], by0);
  float cx = __fadd_rn(bx0, __fmul_rn(px, bw));
  float cy = __fadd_rn(by0, __fmul_rn(py, bh));

  // fine: x = (cx*0.25/256)*256 - 0.5 == cx*0.25 - 0.5 exactly (pow2 scales)
  {
    float gx = __fsub_rn(__fmul_rn(cx, 0.25f), 0.5f);
    float gy = __fsub_rn(__fmul_rn(cy, 0.25f), 0.5f);
    float fxf = floorf(gx), fyf = floorf(gy);
    float fx = __fsub_rn(gx, fxf), fy = __fsub_rn(gy, fyf);
    int x0 = (int)fxf, y0 = (int)fyf;
    float ofx = __fsub_rn(1.f, fx), ofy = __fsub_rn(1.f, fy);
    float w00 = __fmul_rn(ofx, ofy);
    float w10 = __fmul_rn(fx, ofy);
    float w01 = __fmul_rn(ofx, fy);
    float w11 = __fmul_rn(fx, fy);
    bool vx0 = (x0 >= 0) && (x0 < 256), vx1 = (x0 + 1 >= 0) && (x0 + 1 < 256);
    bool vy0 = (y0 >= 0) && (y0 < 256), vy1 = (y0 + 1 >= 0) && (y0 + 1 < 256);
    float W00 = (vx0 && vy0) ? w00 : 0.f;
    float W10 = (vx1 && vy0) ? w10 : 0.f;
    float W01 = (vx0 && vy1) ? w01 : 0.f;
    float W11 = (vx1 && vy1) ? w11 : 0.f;
    int x0c = min(max(x0, 0), 255), x1c = min(max(x0 + 1, 0), 255);
    int y0c = min(max(y0, 0), 255), y1c = min(max(y0 + 1, 0), 255);
    const float* p00 = featT + ((size_t)(y0c * 256 + x0c)) * 256;
    const float* p10 = featT + ((size_t)(y0c * 256 + x1c)) * 256;
    const float* p01 = featT + ((size_t)(y1c * 256 + x0c)) * 256;
    const float* p11 = featT + ((size_t)(y1c * 256 + x1c)) * 256;
    float acc = __fmul_rn(p00[tid], W00);
    acc = __fadd_rn(acc, __fmul_rn(p10[tid], W10));
    acc = __fadd_rn(acc, __fmul_rn(p01[tid], W01));
    acc = __fadd_rn(acc, __fmul_rn(p11[tid], W11));
    X0[(size_t)rp * CIN_ + tid] = acc;
  }

  // coarse: x = px*7 - 0.5 on 7x7, zeros padding
  if (tid < K_) {
    float gx = __fsub_rn(__fmul_rn(px, 7.f), 0.5f);
    float gy = __fsub_rn(__fmul_rn(py, 7.f), 0.5f);
    float fxf = floorf(gx), fyf = floorf(gy);
    float fx = __fsub_rn(gx, fxf), fy = __fsub_rn(gy, fyf);
    int x0 = (int)fxf, y0 = (int)fyf;
    float ofx = __fsub_rn(1.f, fx), ofy = __fsub_rn(1.f, fy);
    float w00 = __fmul_rn(ofx, ofy);
    float w10 = __fmul_rn(fx, ofy);
    float w01 = __fmul_rn(ofx, fy);
    float w11 = __fmul_rn(fx, fy);
    bool vx0 = (x0 >= 0) && (x0 < 7), vx1 = (x0 + 1 >= 0) && (x0 + 1 < 7);
    bool vy0 = (y0 >= 0) && (y0 < 7), vy1 = (y0 + 1 >= 0) && (y0 + 1 < 7);
    float W00 = (vx0 && vy0) ? w00 : 0.f;
    float W10 = (vx1 && vy0) ? w10 : 0.f;
    float W01 = (vx0 && vy1) ? w01 : 0.f;
    float W11 = (vx1 && vy1) ? w11 : 0.f;
    int x0c = min(max(x0, 0), 6), x1c = min(max(x0 + 1, 0), 6);
    int y0c = min(max(y0, 0), 6), y1c = min(max(y0 + 1, 0), 6);
    const float* cb = coarseT + (size_t)r * 49 * K_;
    float acc = __fmul_rn(cb[(size_t)(y0c * 7 + x0c) * K_ + tid], W00);
    acc = __fadd_rn(acc, __fmul_rn(cb[(size_t)(y0c * 7 + x1c) * K_ + tid], W10));
    acc = __fadd_rn(acc, __fmul_rn(cb[(size_t)(y1c * 7 + x0c) * K_ + tid], W01));
    acc = __fadd_rn(acc, __fmul_rn(cb[(size_t)(y1c * 7 + x1c) * K_ + tid], W11));
    X0[(size_t)rp * CIN_ + 256 + tid] = acc;
  }
}

// ---------------- f32 GEMM: out[n][o] = act(sum_k W[o][k]*in[n][k] + b[o]) ----------------
// in = [A1 (k<256) | A2 (k>=256, 81 cols)], K total = 337. Block tile 128x128, thread 8x8.
__global__ __launch_bounds__(256) void gemm_kernel(const float* __restrict__ A1, int ld1,
                                                   const float* __restrict__ A2, int ld2,
                                                   const float* __restrict__ Wm,
                                                   const float* __restrict__ bias,
                                                   float* __restrict__ out, int ldo,
                                                   int O, int N, int relu) {
  __shared__ float Xs[8][132];
  __shared__ float Ws[8][132];
  int n0 = blockIdx.x * 128, o0 = blockIdx.y * 128;
  int tid = threadIdx.x;
  int tn = tid & 15, to = tid >> 4;
  float acc[8][8] = {};
  int lcol = tid & 7, lrow = tid >> 3;  // loader mapping: 8 cols x 32 rows (x4)

  for (int kt = 0; kt < CIN_; kt += 8) {
    int k = kt + lcol;
#pragma unroll
    for (int j = 0; j < 4; ++j) {
      int row = lrow + 32 * j;
      float xv = 0.f, wv = 0.f;
      if (k < CIN_) {
        int n = n0 + row;
        xv = (k < 256) ? A1[(size_t)n * ld1 + k] : A2[(size_t)n * ld2 + (k - 256)];
        int o = o0 + row;
        if (o < O) wv = Wm[(size_t)o * CIN_ + k];
      }
      Xs[lcol][row] = xv;
      Ws[lcol][row] = wv;
    }
    __syncthreads();
#pragma unroll
    for (int kk = 0; kk < 8; ++kk) {
      float4 x0v = *(const float4*)&Xs[kk][tn * 4];
      float4 x1v = *(const float4*)&Xs[kk][64 + tn * 4];
      float4 w0v = *(const float4*)&Ws[kk][to * 4];
      float4 w1v = *(const float4*)&Ws[kk][64 + to * 4];
      float xs[8] = {x0v.x, x0v.y, x0v.z, x0v.w, x1v.x, x1v.y, x1v.z, x1v.w};
      float wsv[8] = {w0v.x, w0v.y, w0v.z, w0v.w, w1v.x, w1v.y, w1v.z, w1v.w};
#pragma unroll
      for (int a = 0; a < 8; ++a)
#pragma unroll
        for (int b = 0; b < 8; ++b)
          acc[a][b] = fmaf(wsv[a], xs[b], acc[a][b]);
    }
    __syncthreads();
  }

#pragma unroll
  for (int a = 0; a < 8; ++a) {
    int o = o0 + ((a < 4) ? (to * 4 + a) : (64 + to * 4 + (a - 4)));
    if (o < O) {
      float bv = bias[o];
#pragma unroll
      for (int b = 0; b < 8; ++b) {
        int n = n0 + ((b < 4) ? (tn * 4 + b) : (64 + tn * 4 + (b - 4)));
        float v = acc[a][b] + bv;
        if (relu) v = fmaxf(v, 0.f);
        out[(size_t)n * ldo + o] = v;
      }
    }
  }
}

// ---------------- scatter head outputs into ml ----------------
__global__ void scatter_kernel(const float* __restrict__ PL, const int* __restrict__ sel,
                               float* __restrict__ ml, int Nlev) {
  int t = blockIdx.x * 256 + threadIdx.x;
  if (t >= R_ * NPTS_ * K_) return;
  int k = t % K_;
  int rp = t / K_;
  int i = sel[rp];
  int r = rp / NPTS_;
  ml[((size_t)r * K_ + k) * Nlev + i] = PL[(size_t)rp * K_ + k];
}

extern "C" void kernel_launch(void* const* d_in, const int* in_sizes, int n_in,
                              void* d_out, int out_size, void* d_ws, size_t ws_size,
                              hipStream_t stream) {
  (void)in_sizes; (void)n_in; (void)out_size; (void)ws_size;
  const float* feat = (const float*)d_in[0];
  const float* bboxes = (const float*)d_in[1];
  const int* labels = (const int*)d_in[2];
  const float* coarse = (const float*)d_in[3];
  const float* W1 = (const float*)d_in[4];
  const float* b1 = (const float*)d_in[5];
  const float* W2 = (const float*)d_in[6];
  const float* b2 = (const float*)d_in[7];
  const float* W3 = (const float*)d_in[8];
  const float* b3 = (const float*)d_in[9];
  const float* Wp = (const float*)d_in[10];
  const float* bp = (const float*)d_in[11];
  float* out = (float*)d_out;
  float* ws = (float*)d_ws;

  float* featT = ws;                     // 16,777,216 f
  float* coarseT = featT + 16777216;     //    254,016 f
  float* ml28 = coarseT + 254016;        //  4,064,256 f
  float* ml56 = ml28 + 4064256;          // 16,257,024 f
  float* X0 = ml56 + 16257024;           // 16,909,312 f  (ml14 aliases head of X0)
  float* Y1 = X0 + 16909312;             // 12,845,056 f
  float* Y2 = Y1 + 12845056;             // 12,845,056 f  (PL aliases Y2)
  int* sel = (int*)(Y2 + 12845056);      //     50,176 i
  float* ml14 = X0;
  float* PL = Y2;

  const int N = R_ * NPTS_;  // 50176

  transpose_feat_kernel<<<dim3(8, 8, 256), dim3(32, 8), 0, stream>>>(feat, featT);
  transpose_coarse_kernel<<<3969, 256, 0, stream>>>(coarse, coarseT);

  // step 0: 7 -> 14 (no refine)
  upsample_kernel<<<3969, 256, 0, stream>>>(coarse, ml14, R_ * K_, 7, 7);
  // step 1: 14 -> 28, refine ALL 784 points
  upsample_kernel<<<15876, 256, 0, stream>>>(ml14, ml28, R_ * K_, 14, 14);
  iota_kernel<<<196, 256, 0, stream>>>(sel);
  sample_kernel<<<N, 256, 0, stream>>>(sel, bboxes, featT, coarseT, X0, 28, 28);
  gemm_kernel<<<dim3(392, 2), 256, 0, stream>>>(X0, CIN_, X0 + 256, CIN_, W1, b1, Y1, 256, 256, N, 1);
  gemm_kernel<<<dim3(392, 2), 256, 0, stream>>>(Y1, 256, X0 + 256, CIN_, W2, b2, Y2, 256, 256, N, 1);
  gemm_kernel<<<dim3(392, 2), 256, 0, stream>>>(Y2, 256, X0 + 256, CIN_, W3, b3, Y1, 256, 256, N, 1);
  gemm_kernel<<<dim3(392, 1), 256, 0, stream>>>(Y1, 256, X0 + 256, CIN_, Wp, bp, PL, K_, K_, N, 0);
  scatter_kernel<<<15876, 256, 0, stream>>>(PL, sel, ml28, 784);

  // step 2: 28 -> 56, refine top-784 of 3136
  upsample_kernel<<<63504, 256, 0, stream>>>(ml28, ml56, R_ * K_, 28, 28);
  topk_kernel<<<R_, 256, 0, stream>>>(ml56, labels, 3136, sel);
  sample_kernel<<<N, 256, 0, stream>>>(sel, bboxes, featT, coarseT, X0, 56, 56);
  gemm_kernel<<<dim3(392, 2), 256, 0, stream>>>(X0, CIN_, X0 + 256, CIN_, W1, b1, Y1, 256, 256, N, 1);
  gemm_kernel<<<dim3(392, 2), 256, 0, stream>>>(Y1, 256, X0 + 256, CIN_, W2, b2, Y2, 256, 256, N, 1);
  gemm_kernel<<<dim3(392, 2), 256, 0, stream>>>(Y2, 256, X0 + 256, CIN_, W3, b3, Y1, 256, 256, N, 1);
  gemm_kernel<<<dim3(392, 1), 256, 0, stream>>>(Y1, 256, X0 + 256, CIN_, Wp, bp, PL, K_, K_, N, 0);
  scatter_kernel<<<15876, 256, 0, stream>>>(PL, sel, ml56, 3136);

  // step 3: 56 -> 112 (into d_out), refine top-784 of 12544
  upsample_kernel<<<254016, 256, 0, stream>>>(ml56, out, R_ * K_, 56, 56);
  topk_kernel<<<R_, 256, 0, stream>>>(out, labels, 12544, sel);
  sample_kernel<<<N, 256, 0, stream>>>(sel, bboxes, featT, coarseT, X0, 112, 112);
  gemm_kernel<<<dim3(392, 2), 256, 0, stream>>>(X0, CIN_, X0 + 256, CIN_, W1, b1, Y1, 256, 256, N, 1);
  gemm_kernel<<<dim3(392, 2), 256, 0, stream>>>(Y1, 256, X0 + 256, CIN_, W2, b2, Y2, 256, 256, N, 1);
  gemm_kernel<<<dim3(392, 2), 256, 0, stream>>>(Y2, 256, X0 + 256, CIN_, W3, b3, Y1, 256, 256, N, 1);
  gemm_kernel<<<dim3(392, 1), 256, 0, stream>>>(Y1, 256, X0 + 256, CIN_, Wp, bp, PL, K_, K_, N, 0);
  scatter_kernel<<<15876, 256, 0, stream>>>(PL, sel, out, 12544);
}

// Round 2
// 1179.095 us; speedup vs baseline: 2.6295x; 2.6295x over previous
//
#include <hip/hip_runtime.h>
#include <hip/hip_bf16.h>
#include <cstdint>
#include <cstddef>

#define R_ 64
#define K_ 81
#define NPTS_ 784

typedef __attribute__((ext_vector_type(8))) short short8;
typedef __attribute__((ext_vector_type(4))) float f32x4;

#define GLDS16(G, L)                                                           \
  __builtin_amdgcn_global_load_lds(                                            \
      (__attribute__((address_space(1))) void*)(void*)(G),                     \
      (__attribute__((address_space(3))) void*)(L), 16, 0, 0)

// ---------------- transpose feat [C][H][W] -> [H][W][C] ----------------
__global__ __launch_bounds__(256) void transpose_feat_kernel(const float* __restrict__ in,
                                                             float* __restrict__ out) {
  __shared__ float tile[32][33];
  int y = blockIdx.z;
  int x0 = blockIdx.x * 32, c0 = blockIdx.y * 32;
  int tx = threadIdx.x, ty = threadIdx.y;
#pragma unroll
  for (int j = 0; j < 32; j += 8)
    tile[ty + j][tx] = in[(size_t)(c0 + ty + j) * 65536 + (size_t)y * 256 + x0 + tx];
  __syncthreads();
#pragma unroll
  for (int j = 0; j < 32; j += 8)
    out[((size_t)y * 256 + (x0 + ty + j)) * 256 + c0 + tx] = tile[tx][ty + j];
}

// ---------------- transpose coarse [R][K][49] -> [R][49][K] ----------------
__global__ void transpose_coarse_kernel(const float* __restrict__ in, float* __restrict__ out) {
  int t = blockIdx.x * 256 + threadIdx.x;
  if (t >= R_ * 49 * K_) return;
  int k = t % K_;
  int t2 = t / K_;
  int pos = t2 % 49;
  int r = t2 / 49;
  out[t] = in[((size_t)r * K_ + k) * 49 + pos];
}

// ---------------- split weights into hi/lo bf16, pad K to 352, pad Wp rows to 128 ----------------
__global__ void prep_weights_kernel(const float* __restrict__ W1, const float* __restrict__ W2,
                                    const float* __restrict__ W3, const float* __restrict__ Wp,
                                    const float* __restrict__ bp,
                                    __hip_bfloat16* __restrict__ WH, __hip_bfloat16* __restrict__ WL,
                                    float* __restrict__ bp128) {
  int t = blockIdx.x * 256 + threadIdx.x;
  if (t < 896 * 352) {
    int row = t / 352, col = t % 352;
    float v = 0.f;
    if (col < 337) {
      if (row < 256) v = W1[row * 337 + col];
      else if (row < 512) v = W2[(row - 256) * 337 + col];
      else if (row < 768) v = W3[(row - 512) * 337 + col];
      else if (row - 768 < 81) v = Wp[(row - 768) * 337 + col];
    }
    __hip_bfloat16 h = __float2bfloat16(v);
    WH[t] = h;
    WL[t] = __float2bfloat16(v - __bfloat162float(h));
  } else if (t < 896 * 352 + 128) {
    int k = t - 896 * 352;
    bp128[k] = (k < 81) ? bp[k] : 0.f;
  }
}

// ---------------- 2x bilinear upsample (jax.image.resize linear semantics) ----------------
__global__ void upsample_kernel(const float* __restrict__ in, float* __restrict__ out,
                                int B, int Hin, int Win) {
  int Wout = 2 * Win, Hout = 2 * Hin;
  size_t total = (size_t)B * Hout * Wout;
  size_t t = (size_t)blockIdx.x * 256 + threadIdx.x;
  if (t >= total) return;
  int ox = (int)(t % Wout);
  size_t t2 = t / Wout;
  int oy = (int)(t2 % Hout);
  int b = (int)(t2 / Hout);
  float sx = 0.5f * (float)ox - 0.25f;
  float sy = 0.5f * (float)oy - 0.25f;
  int x0, x1;
  float wx1;
  if (sx < 0.f) { x0 = 0; x1 = 0; wx1 = 0.f; }
  else if (sx >= (float)(Win - 1)) { x0 = Win - 1; x1 = Win - 1; wx1 = 0.f; }
  else { x0 = (int)sx; x1 = x0 + 1; wx1 = sx - (float)x0; }
  float wx0 = 1.f - wx1;
  int y0, y1;
  float wy1;
  if (sy < 0.f) { y0 = 0; y1 = 0; wy1 = 0.f; }
  else if (sy >= (float)(Hin - 1)) { y0 = Hin - 1; y1 = Hin - 1; wy1 = 0.f; }
  else { y0 = (int)sy; y1 = y0 + 1; wy1 = sy - (float)y0; }
  float wy0 = 1.f - wy1;
  const float* p = in + (size_t)b * Hin * Win;
  float r0 = wx0 * p[(size_t)y0 * Win + x0] + wx1 * p[(size_t)y0 * Win + x1];
  float r1 = wx0 * p[(size_t)y1 * Win + x0] + wx1 * p[(size_t)y1 * Win + x1];
  out[t] = wy0 * r0 + wy1 * r1;
}

// ---------------- iota selection (step 1: all 784 points) ----------------
__global__ void iota_kernel(int* __restrict__ sel) {
  int t = blockIdx.x * 256 + threadIdx.x;
  if (t < R_ * NPTS_) sel[t] = t % NPTS_;
}

// ---------------- per-ROI top-784 smallest |gt| (jax top_k tie semantics) ----------------
__global__ __launch_bounds__(256) void topk_kernel(const float* __restrict__ ml,
                                                   const int* __restrict__ labels,
                                                   int N, int* __restrict__ sel) {
  int r = blockIdx.x;
  const float* gt = ml + ((size_t)r * K_ + (labels[r] + 1)) * N;
  __shared__ unsigned int hist[256];
  __shared__ unsigned int sh_prefix, sh_remaining, sh_countless;
  int tid = threadIdx.x;

  unsigned int prefix = 0;
  unsigned int remaining = NPTS_;
  unsigned int count_less = 0;
  for (int pass = 0; pass < 4; ++pass) {
    int shift = 24 - 8 * pass;
    hist[tid] = 0;
    __syncthreads();
    for (int i = tid; i < N; i += 256) {
      unsigned int v = __float_as_uint(fabsf(gt[i]));
      bool match = (pass == 0) || ((v >> (shift + 8)) == prefix);
      if (match) atomicAdd(&hist[(v >> shift) & 255u], 1u);
    }
    __syncthreads();
    if (tid == 0) {
      unsigned int cum = 0, before = 0;
      int d = 255;
      for (int dd = 0; dd < 256; ++dd) {
        unsigned int c = hist[dd];
        if (cum + c >= remaining) { before = cum; d = dd; break; }
        cum += c;
      }
      sh_prefix = (prefix << 8) | (unsigned int)d;
      sh_remaining = remaining - before;
      sh_countless = count_less + before;
    }
    __syncthreads();
    prefix = sh_prefix;
    remaining = sh_remaining;
    count_less = sh_countless;
    __syncthreads();
  }
  unsigned int vstar = prefix;
  unsigned int need_eq = NPTS_ - count_less;

  __shared__ unsigned int wtot_less[4], wtot_eq[4];
  unsigned int base_less = 0, base_eq = 0;
  int lane = tid & 63, wv = tid >> 6;
  int* selr = sel + (size_t)r * NPTS_;
  for (int base = 0; base < N; base += 256) {
    int i = base + tid;
    bool less = false, eq = false;
    if (i < N) {
      unsigned int v = __float_as_uint(fabsf(gt[i]));
      less = v < vstar;
      eq = v == vstar;
    }
    unsigned long long ml_ = __ballot(less);
    unsigned long long me_ = __ballot(eq);
    unsigned long long lanemask = (lane == 0) ? 0ull : ((~0ull) >> (64 - lane));
    unsigned int pl = __popcll(ml_ & lanemask);
    unsigned int pe = __popcll(me_ & lanemask);
    if (lane == 0) { wtot_less[wv] = (unsigned int)__popcll(ml_); wtot_eq[wv] = (unsigned int)__popcll(me_); }
    __syncthreads();
    unsigned int off_l = 0, off_e = 0, tot_l = 0, tot_e = 0;
#pragma unroll
    for (int w2 = 0; w2 < 4; ++w2) {
      unsigned int tl = wtot_less[w2], te = wtot_eq[w2];
      if (w2 < wv) { off_l += tl; off_e += te; }
      tot_l += tl;
      tot_e += te;
    }
    if (less) selr[base_less + off_l + pl] = i;
    if (eq) {
      unsigned int er = base_eq + off_e + pe;
      if (er < need_eq) selr[count_less + er] = i;
    }
    base_less += tot_l;
    base_eq += tot_e;
    __syncthreads();
  }
}

// ---------------- sample fine + coarse; write hi/lo bf16 splits ----------------
__global__ __launch_bounds__(256) void sample_kernel(const int* __restrict__ sel,
                                                     const float* __restrict__ bboxes,
                                                     const float* __restrict__ featT,
                                                     const float* __restrict__ coarseT,
                                                     __hip_bfloat16* __restrict__ Xh,
                                                     __hip_bfloat16* __restrict__ Xl,
                                                     __hip_bfloat16* __restrict__ Cth,
                                                     __hip_bfloat16* __restrict__ Ctl,
                                                     int Wlev, int Hlev) {
  int rp = blockIdx.x;
  int r = rp / NPTS_;
  int idx = sel[rp];
  int tid = threadIdx.x;

  float px = ((float)(idx % Wlev) + 0.5f) / (float)Wlev;
  float py = ((float)(idx / Wlev) + 0.5f) / (float)Hlev;
  float bx0 = bboxes[r * 4 + 0], by0 = bboxes[r * 4 + 1];
  float bw = __fsub_rn(bboxes[r * 4 + 2], bx0);
  float bh = __fsub_rn(bboxes[r * 4 + 3], by0);
  float cx = __fadd_rn(bx0, __fmul_rn(px, bw));
  float cy = __fadd_rn(by0, __fmul_rn(py, bh));

  {
    float gx = __fsub_rn(__fmul_rn(cx, 0.25f), 0.5f);
    float gy = __fsub_rn(__fmul_rn(cy, 0.25f), 0.5f);
    float fxf = floorf(gx), fyf = floorf(gy);
    float fx = __fsub_rn(gx, fxf), fy = __fsub_rn(gy, fyf);
    int x0 = (int)fxf, y0 = (int)fyf;
    float ofx = __fsub_rn(1.f, fx), ofy = __fsub_rn(1.f, fy);
    float w00 = __fmul_rn(ofx, ofy);
    float w10 = __fmul_rn(fx, ofy);
    float w01 = __fmul_rn(ofx, fy);
    float w11 = __fmul_rn(fx, fy);
    bool vx0 = (x0 >= 0) && (x0 < 256), vx1 = (x0 + 1 >= 0) && (x0 + 1 < 256);
    bool vy0 = (y0 >= 0) && (y0 < 256), vy1 = (y0 + 1 >= 0) && (y0 + 1 < 256);
    float W00 = (vx0 && vy0) ? w00 : 0.f;
    float W10 = (vx1 && vy0) ? w10 : 0.f;
    float W01 = (vx0 && vy1) ? w01 : 0.f;
    float W11 = (vx1 && vy1) ? w11 : 0.f;
    int x0c = min(max(x0, 0), 255), x1c = min(max(x0 + 1, 0), 255);
    int y0c = min(max(y0, 0), 255), y1c = min(max(y0 + 1, 0), 255);
    const float* p00 = featT + ((size_t)(y0c * 256 + x0c)) * 256;
    const float* p10 = featT + ((size_t)(y0c * 256 + x1c)) * 256;
    const float* p01 = featT + ((size_t)(y1c * 256 + x0c)) * 256;
    const float* p11 = featT + ((size_t)(y1c * 256 + x1c)) * 256;
    float acc = __fmul_rn(p00[tid], W00);
    acc = __fadd_rn(acc, __fmul_rn(p10[tid], W10));
    acc = __fadd_rn(acc, __fmul_rn(p01[tid], W01));
    acc = __fadd_rn(acc, __fmul_rn(p11[tid], W11));
    __hip_bfloat16 h = __float2bfloat16(acc);
    Xh[(size_t)rp * 256 + tid] = h;
    Xl[(size_t)rp * 256 + tid] = __float2bfloat16(acc - __bfloat162float(h));
  }

  if (tid < 96) {
    float acc = 0.f;
    if (tid < K_) {
      float gx = __fsub_rn(__fmul_rn(px, 7.f), 0.5f);
      float gy = __fsub_rn(__fmul_rn(py, 7.f), 0.5f);
      float fxf = floorf(gx), fyf = floorf(gy);
      float fx = __fsub_rn(gx, fxf), fy = __fsub_rn(gy, fyf);
      int x0 = (int)fxf, y0 = (int)fyf;
      float ofx = __fsub_rn(1.f, fx), ofy = __fsub_rn(1.f, fy);
      float w00 = __fmul_rn(ofx, ofy);
      float w10 = __fmul_rn(fx, ofy);
      float w01 = __fmul_rn(ofx, fy);
      float w11 = __fmul_rn(fx, fy);
      bool vx0 = (x0 >= 0) && (x0 < 7), vx1 = (x0 + 1 >= 0) && (x0 + 1 < 7);
      bool vy0 = (y0 >= 0) && (y0 < 7), vy1 = (y0 + 1 >= 0) && (y0 + 1 < 7);
      float W00 = (vx0 && vy0) ? w00 : 0.f;
      float W10 = (vx1 && vy0) ? w10 : 0.f;
      float W01 = (vx0 && vy1) ? w01 : 0.f;
      float W11 = (vx1 && vy1) ? w11 : 0.f;
      int x0c = min(max(x0, 0), 6), x1c = min(max(x0 + 1, 0), 6);
      int y0c = min(max(y0, 0), 6), y1c = min(max(y0 + 1, 0), 6);
      const float* cb = coarseT + (size_t)r * 49 * K_;
      acc = __fmul_rn(cb[(size_t)(y0c * 7 + x0c) * K_ + tid], W00);
      acc = __fadd_rn(acc, __fmul_rn(cb[(size_t)(y0c * 7 + x1c) * K_ + tid], W10));
      acc = __fadd_rn(acc, __fmul_rn(cb[(size_t)(y1c * 7 + x0c) * K_ + tid], W01));
      acc = __fadd_rn(acc, __fmul_rn(cb[(size_t)(y1c * 7 + x1c) * K_ + tid], W11));
    }
    __hip_bfloat16 h = __float2bfloat16(acc);
    Cth[(size_t)rp * 96 + tid] = h;
    Ctl[(size_t)rp * 96 + tid] = __float2bfloat16(acc - __bfloat162float(h));
  }
}

// ---------------- MFMA GEMM: out[m][o] = act(sum_k W[o][k]*A[m][k] + b[o]) ----------------
// A split: k<256 from Ah/Al [M][256]; k>=256 from Th/Tl [M][96] (cols 81..95 zero).
// W from Wh/Wl [.][352] (zero-padded). 3-term bf16 split: Ah*Wh + Ah*Wl + Al*Wh.
// Block 128x128, 4 waves of 64x64. relu_mode=1: bias+relu, split-write bf16 hi/lo [M][256].
// relu_mode=0: bias, write f32 [M][128].
__global__ __launch_bounds__(256) void mfma_gemm_kernel(
    const __hip_bfloat16* __restrict__ Ah, const __hip_bfloat16* __restrict__ Al,
    const __hip_bfloat16* __restrict__ Th, const __hip_bfloat16* __restrict__ Tl,
    const __hip_bfloat16* __restrict__ Wh, const __hip_bfloat16* __restrict__ Wl,
    const float* __restrict__ bias,
    void* __restrict__ outH, void* __restrict__ outL, int relu_mode) {
  __shared__ char lds[65536];
  const int tid = threadIdx.x;
  const int lane = tid & 63;
  const int w = tid >> 6;
  const int m0 = blockIdx.x * 128;
  const int o0 = blockIdx.y * 128;
  const int wm = w >> 1, wn = w & 1;

  f32x4 acc[4][4];
#pragma unroll
  for (int i = 0; i < 4; ++i)
#pragma unroll
    for (int j = 0; j < 4; ++j) acc[i][j] = (f32x4){0.f, 0.f, 0.f, 0.f};

  const int srow0 = w * 16 + (lane >> 2);
  const int sp = lane & 3;

  auto stage = [&](int kt, int buf) {
    char* base = lds + buf * 32768;
#pragma unroll
    for (int c = 0; c < 2; ++c) {
      const int row = c * 64 + srow0;
      const int s = sp ^ ((row >> 1) & 3);
      char* ldst = base + (c * 64 + w * 16) * 64;
      const char *ga_h, *ga_l;
      if (kt < 8) {
        size_t off = (((size_t)(m0 + row)) * 256 + (size_t)kt * 32 + (size_t)s * 8) * 2;
        ga_h = (const char*)Ah + off;
        ga_l = (const char*)Al + off;
      } else {
        size_t off = (((size_t)(m0 + row)) * 96 + (size_t)(kt - 8) * 32 + (size_t)s * 8) * 2;
        ga_h = (const char*)Th + off;
        ga_l = (const char*)Tl + off;
      }
      GLDS16(ga_h, ldst);
      GLDS16(ga_l, ldst + 8192);
      size_t woff = (((size_t)(o0 + row)) * 352 + (size_t)kt * 32 + (size_t)s * 8) * 2;
      GLDS16((const char*)Wh + woff, ldst + 16384);
      GLDS16((const char*)Wl + woff, ldst + 24576);
    }
  };

  stage(0, 0);
  asm volatile("s_waitcnt vmcnt(0)" ::: "memory");
  __syncthreads();
  int cur = 0;
  for (int kt = 0; kt < 11; ++kt) {
    if (kt < 10) stage(kt + 1, cur ^ 1);
    const char* Atile_h = lds + cur * 32768;
    const char* Atile_l = Atile_h + 8192;
    const char* Btile_h = Atile_h + 16384;
    const char* Btile_l = Atile_h + 24576;
    short8 ah[4], al[4], bh[4], bl[4];
    const int g = lane >> 4;
#pragma unroll
    for (int i = 0; i < 4; ++i) {
      int rowA = wm * 64 + i * 16 + (lane & 15);
      int offA = rowA * 64 + ((g ^ ((rowA >> 1) & 3)) << 4);
      ah[i] = *(const short8*)(Atile_h + offA);
      al[i] = *(const short8*)(Atile_l + offA);
      int rowB = wn * 64 + i * 16 + (lane & 15);
      int offB = rowB * 64 + ((g ^ ((rowB >> 1) & 3)) << 4);
      bh[i] = *(const short8*)(Btile_h + offB);
      bl[i] = *(const short8*)(Btile_l + offB);
    }
#pragma unroll
    for (int i = 0; i < 4; ++i)
#pragma unroll
      for (int j = 0; j < 4; ++j) {
        acc[i][j] = __builtin_amdgcn_mfma_f32_16x16x32_bf16(ah[i], bh[j], acc[i][j], 0, 0, 0);
        acc[i][j] = __builtin_amdgcn_mfma_f32_16x16x32_bf16(ah[i], bl[j], acc[i][j], 0, 0, 0);
        acc[i][j] = __builtin_amdgcn_mfma_f32_16x16x32_bf16(al[i], bh[j], acc[i][j], 0, 0, 0);
      }
    asm volatile("s_waitcnt vmcnt(0)" ::: "memory");
    __syncthreads();
    cur ^= 1;
  }

  if (relu_mode) {
    __hip_bfloat16* oh = (__hip_bfloat16*)outH;
    __hip_bfloat16* ol = (__hip_bfloat16*)outL;
#pragma unroll
    for (int j = 0; j < 4; ++j) {
      int o = o0 + wn * 64 + j * 16 + (lane & 15);
      float bv = bias[o];
#pragma unroll
      for (int i = 0; i < 4; ++i) {
        int mbase = m0 + wm * 64 + i * 16 + (lane >> 4) * 4;
#pragma unroll
        for (int r = 0; r < 4; ++r) {
          float v = fmaxf(acc[i][j][r] + bv, 0.f);
          __hip_bfloat16 h = __float2bfloat16(v);
          size_t idx = (size_t)(mbase + r) * 256 + o;
          oh[idx] = h;
          ol[idx] = __float2bfloat16(v - __bfloat162float(h));
        }
      }
    }
  } else {
    float* op = (float*)outH;
#pragma unroll
    for (int j = 0; j < 4; ++j) {
      int o = o0 + wn * 64 + j * 16 + (lane & 15);
      float bv = bias[o];
#pragma unroll
      for (int i = 0; i < 4; ++i) {
        int mbase = m0 + wm * 64 + i * 16 + (lane >> 4) * 4;
#pragma unroll
        for (int r = 0; r < 4; ++r) {
          op[(size_t)(mbase + r) * 128 + o] = acc[i][j][r] + bv;
        }
      }
    }
  }
}

// ---------------- scatter head outputs into ml ----------------
__global__ void scatter_kernel(const float* __restrict__ PL, const int* __restrict__ sel,
                               float* __restrict__ ml, int Nlev) {
  int t = blockIdx.x * 256 + threadIdx.x;
  if (t >= R_ * NPTS_ * K_) return;
  int k = t % K_;
  int rp = t / K_;
  int i = sel[rp];
  int r = rp / NPTS_;
  ml[((size_t)r * K_ + k) * Nlev + i] = PL[(size_t)rp * 128 + k];
}

extern "C" void kernel_launch(void* const* d_in, const int* in_sizes, int n_in,
                              void* d_out, int out_size, void* d_ws, size_t ws_size,
                              hipStream_t stream) {
  (void)in_sizes; (void)n_in; (void)out_size; (void)ws_size;
  const float* feat = (const float*)d_in[0];
  const float* bboxes = (const float*)d_in[1];
  const int* labels = (const int*)d_in[2];
  const float* coarse = (const float*)d_in[3];
  const float* W1 = (const float*)d_in[4];
  const float* b1 = (const float*)d_in[5];
  const float* W2 = (const float*)d_in[6];
  const float* b2 = (const float*)d_in[7];
  const float* W3 = (const float*)d_in[8];
  const float* b3 = (const float*)d_in[9];
  const float* Wp = (const float*)d_in[10];
  const float* bp = (const float*)d_in[11];
  float* out = (float*)d_out;

  char* p = (char*)d_ws;
  auto alloc = [&](size_t bytes) { char* r = p; p += (bytes + 255) & ~(size_t)255; return r; };
  float* featT = (float*)alloc(16777216ull * 4);
  float* coarseT = (float*)alloc(254016ull * 4);
  float* ml14 = (float*)alloc(1016064ull * 4);
  float* ml28 = (float*)alloc(4064256ull * 4);
  float* ml56 = (float*)alloc(16257024ull * 4);
  float* PL = (float*)alloc(6422528ull * 4);
  int* sel = (int*)alloc(50176ull * 4);
  __hip_bfloat16* Xa_h = (__hip_bfloat16*)alloc(12845056ull * 2);
  __hip_bfloat16* Xa_l = (__hip_bfloat16*)alloc(12845056ull * 2);
  __hip_bfloat16* Xb_h = (__hip_bfloat16*)alloc(12845056ull * 2);
  __hip_bfloat16* Xb_l = (__hip_bfloat16*)alloc(12845056ull * 2);
  __hip_bfloat16* Ct_h = (__hip_bfloat16*)alloc(4816896ull * 2);
  __hip_bfloat16* Ct_l = (__hip_bfloat16*)alloc(4816896ull * 2);
  __hip_bfloat16* WH = (__hip_bfloat16*)alloc(315392ull * 2);
  __hip_bfloat16* WL = (__hip_bfloat16*)alloc(315392ull * 2);
  float* bp128 = (float*)alloc(128ull * 4);

  const int N = R_ * NPTS_;  // 50176

  transpose_feat_kernel<<<dim3(8, 8, 256), dim3(32, 8), 0, stream>>>(feat, featT);
  transpose_coarse_kernel<<<3969, 256, 0, stream>>>(coarse, coarseT);
  prep_weights_kernel<<<1233, 256, 0, stream>>>(W1, W2, W3, Wp, bp, WH, WL, bp128);

  const __hip_bfloat16* W1h = WH;
  const __hip_bfloat16* W2h = WH + 256 * 352;
  const __hip_bfloat16* W3h = WH + 512 * 352;
  const __hip_bfloat16* Wph = WH + 768 * 352;
  const __hip_bfloat16* W1l = WL;
  const __hip_bfloat16* W2l = WL + 256 * 352;
  const __hip_bfloat16* W3l = WL + 512 * 352;
  const __hip_bfloat16* Wpl = WL + 768 * 352;

  // step 0: 7 -> 14 (no refine)
  upsample_kernel<<<3969, 256, 0, stream>>>(coarse, ml14, R_ * K_, 7, 7);

  for (int step = 1; step <= 3; ++step) {
    if (step == 1) {
      upsample_kernel<<<15876, 256, 0, stream>>>(ml14, ml28, R_ * K_, 14, 14);
      iota_kernel<<<196, 256, 0, stream>>>(sel);
      sample_kernel<<<N, 256, 0, stream>>>(sel, bboxes, featT, coarseT, Xa_h, Xa_l, Ct_h, Ct_l, 28, 28);
    } else if (step == 2) {
      upsample_kernel<<<63504, 256, 0, stream>>>(ml28, ml56, R_ * K_, 28, 28);
      topk_kernel<<<R_, 256, 0, stream>>>(ml56, labels, 3136, sel);
      sample_kernel<<<N, 256, 0, stream>>>(sel, bboxes, featT, coarseT, Xa_h, Xa_l, Ct_h, Ct_l, 56, 56);
    } else {
      upsample_kernel<<<254016, 256, 0, stream>>>(ml56, out, R_ * K_, 56, 56);
      topk_kernel<<<R_, 256, 0, stream>>>(out, labels, 12544, sel);
      sample_kernel<<<N, 256, 0, stream>>>(sel, bboxes, featT, coarseT, Xa_h, Xa_l, Ct_h, Ct_l, 112, 112);
    }
    mfma_gemm_kernel<<<dim3(392, 2), 256, 0, stream>>>(Xa_h, Xa_l, Ct_h, Ct_l, W1h, W1l, b1, Xb_h, Xb_l, 1);
    mfma_gemm_kernel<<<dim3(392, 2), 256, 0, stream>>>(Xb_h, Xb_l, Ct_h, Ct_l, W2h, W2l, b2, Xa_h, Xa_l, 1);
    mfma_gemm_kernel<<<dim3(392, 2), 256, 0, stream>>>(Xa_h, Xa_l, Ct_h, Ct_l, W3h, W3l, b3, Xb_h, Xb_l, 1);
    mfma_gemm_kernel<<<dim3(392, 1), 256, 0, stream>>>(Xb_h, Xb_l, Ct_h, Ct_l, Wph, Wpl, bp128, PL, nullptr, 0);
    if (step == 1) scatter_kernel<<<15876, 256, 0, stream>>>(PL, sel, ml28, 784);
    else if (step == 2) scatter_kernel<<<15876, 256, 0, stream>>>(PL, sel, ml56, 3136);
    else scatter_kernel<<<15876, 256, 0, stream>>>(PL, sel, out, 12544);
  }
}

// Round 3
// 1036.021 us; speedup vs baseline: 2.9927x; 1.1381x over previous
//
#include <hip/hip_runtime.h>
#include <hip/hip_bf16.h>
#include <cstdint>
#include <cstddef>

#define R_ 64
#define K_ 81
#define NPTS_ 784

typedef __attribute__((ext_vector_type(8))) short short8;
typedef __attribute__((ext_vector_type(4))) float f32x4;

#define GLDS16(G, L)                                                           \
  __builtin_amdgcn_global_load_lds(                                            \
      (__attribute__((address_space(1))) void*)(void*)(G),                     \
      (__attribute__((address_space(3))) void*)(L), 16, 0, 0)

// ---------------- transpose feat [C][H][W] -> [H][W][C] ----------------
__global__ __launch_bounds__(256) void transpose_feat_kernel(const float* __restrict__ in,
                                                             float* __restrict__ out) {
  __shared__ float tile[32][33];
  int y = blockIdx.z;
  int x0 = blockIdx.x * 32, c0 = blockIdx.y * 32;
  int tx = threadIdx.x, ty = threadIdx.y;
#pragma unroll
  for (int j = 0; j < 32; j += 8)
    tile[ty + j][tx] = in[(size_t)(c0 + ty + j) * 65536 + (size_t)y * 256 + x0 + tx];
  __syncthreads();
#pragma unroll
  for (int j = 0; j < 32; j += 8)
    out[((size_t)y * 256 + (x0 + ty + j)) * 256 + c0 + tx] = tile[tx][ty + j];
}

// ---------------- transpose coarse [R][K][49] -> [R][49][K] ----------------
__global__ void transpose_coarse_kernel(const float* __restrict__ in, float* __restrict__ out) {
  int t = blockIdx.x * 256 + threadIdx.x;
  if (t >= R_ * 49 * K_) return;
  int k = t % K_;
  int t2 = t / K_;
  int pos = t2 % 49;
  int r = t2 / 49;
  out[t] = in[((size_t)r * K_ + k) * 49 + pos];
}

// ---------------- split weights into hi/lo bf16, pad K to 352, pad Wp rows to 128 ----------------
__global__ void prep_weights_kernel(const float* __restrict__ W1, const float* __restrict__ W2,
                                    const float* __restrict__ W3, const float* __restrict__ Wp,
                                    const float* __restrict__ bp,
                                    __hip_bfloat16* __restrict__ WH, __hip_bfloat16* __restrict__ WL,
                                    float* __restrict__ bp128) {
  int t = blockIdx.x * 256 + threadIdx.x;
  if (t < 896 * 352) {
    int row = t / 352, col = t % 352;
    float v = 0.f;
    if (col < 337) {
      if (row < 256) v = W1[row * 337 + col];
      else if (row < 512) v = W2[(row - 256) * 337 + col];
      else if (row < 768) v = W3[(row - 512) * 337 + col];
      else if (row - 768 < 81) v = Wp[(row - 768) * 337 + col];
    }
    __hip_bfloat16 h = __float2bfloat16(v);
    WH[t] = h;
    WL[t] = __float2bfloat16(v - __bfloat162float(h));
  } else if (t < 896 * 352 + 128) {
    int k = t - 896 * 352;
    bp128[k] = (k < 81) ? bp[k] : 0.f;
  }
}

// ---------------- 2x bilinear upsample, quad form (jax.image.resize linear semantics) ----
// One thread per INPUT pixel (iy,ix) computes the 2x2 output quad. Weights match the
// reference exactly: even out-col: wx1 = (ix==0)?0:0.75, x0=ix-1|0, x1=ix;
// odd out-col: wx1 = (ix==Win-1)?0:0.25, x0=ix, x1=ix+1. Same for rows.
__global__ __launch_bounds__(128) void upsample2x_kernel(const float* __restrict__ in,
                                                         float* __restrict__ out,
                                                         int Hin, int Win) {
  int b = blockIdx.z;
  int iy = blockIdx.y * 2 + threadIdx.y;
  int ix = blockIdx.x * 64 + threadIdx.x;
  if (ix >= Win || iy >= Hin) return;
  const float* p = in + (size_t)b * Hin * Win;
  int rT = (iy == 0) ? 0 : iy - 1;
  int rB = (iy == Hin - 1) ? iy : iy + 1;
  int cL = (ix == 0) ? 0 : ix - 1;
  int cR = (ix == Win - 1) ? ix : ix + 1;
  float wyT1 = (iy == 0) ? 0.f : 0.75f;        // top out row: weight on y1(=iy)
  float wyB1 = (iy == Hin - 1) ? 0.f : 0.25f;  // bottom out row: weight on y1(=iy+1)
  float wxE1 = (ix == 0) ? 0.f : 0.75f;        // even out col: weight on x1(=ix)
  float wxO1 = (ix == Win - 1) ? 0.f : 0.25f;  // odd out col: weight on x1(=ix+1)
  float wyT0 = 1.f - wyT1, wyB0 = 1.f - wyB1;
  float wxE0 = 1.f - wxE1, wxO0 = 1.f - wxO1;

  const float* rowA = p + (size_t)rT * Win;  // iy-1 (clamped)
  const float* rowM = p + (size_t)iy * Win;  // iy
  const float* rowC = p + (size_t)rB * Win;  // iy+1 (clamped)
  float al = rowA[cL], am = rowA[ix], ar = rowA[cR];
  float mL = rowM[cL], mm = rowM[ix], mr = rowM[cR];
  float cl = rowC[cL], cm = rowC[ix], cr = rowC[cR];

  // horizontal mixes per row (r0-style: wx0*p[x0] + wx1*p[x1])
  float aE = wxE0 * al + wxE1 * am;
  float aO = wxO0 * am + wxO1 * ar;
  float mE = wxE0 * mL + wxE1 * mm;
  float mO = wxO0 * mm + wxO1 * mr;
  float cE = wxE0 * cl + wxE1 * cm;
  float cO = wxO0 * cm + wxO1 * cr;

  // vertical mixes (out = wy0*r0 + wy1*r1)
  float oTE = wyT0 * aE + wyT1 * mE;
  float oTO = wyT0 * aO + wyT1 * mO;
  float oBE = wyB0 * mE + wyB1 * cE;
  float oBO = wyB0 * mO + wyB1 * cO;

  int Wout = 2 * Win;
  float* ob = out + ((size_t)b * (2 * Hin) + 2 * iy) * Wout + 2 * ix;
  *(float2*)ob = make_float2(oTE, oTO);
  *(float2*)(ob + Wout) = make_float2(oBE, oBO);
}

// ---------------- iota selection (step 1: all 784 points) ----------------
__global__ void iota_kernel(int* __restrict__ sel) {
  int t = blockIdx.x * 256 + threadIdx.x;
  if (t < R_ * NPTS_) sel[t] = t % NPTS_;
}

// ---------------- per-ROI top-784 smallest |gt| (jax top_k tie semantics) ----------------
__global__ __launch_bounds__(256) void topk_kernel(const float* __restrict__ ml,
                                                   const int* __restrict__ labels,
                                                   int N, int* __restrict__ sel) {
  int r = blockIdx.x;
  const float* gt = ml + ((size_t)r * K_ + (labels[r] + 1)) * N;
  __shared__ unsigned int hist[256];
  __shared__ unsigned int sh_prefix, sh_remaining, sh_countless;
  int tid = threadIdx.x;

  unsigned int prefix = 0;
  unsigned int remaining = NPTS_;
  unsigned int count_less = 0;
  for (int pass = 0; pass < 4; ++pass) {
    int shift = 24 - 8 * pass;
    hist[tid] = 0;
    __syncthreads();
    for (int i = tid; i < N; i += 256) {
      unsigned int v = __float_as_uint(fabsf(gt[i]));
      bool match = (pass == 0) || ((v >> (shift + 8)) == prefix);
      if (match) atomicAdd(&hist[(v >> shift) & 255u], 1u);
    }
    __syncthreads();
    if (tid == 0) {
      unsigned int cum = 0, before = 0;
      int d = 255;
      for (int dd = 0; dd < 256; ++dd) {
        unsigned int c = hist[dd];
        if (cum + c >= remaining) { before = cum; d = dd; break; }
        cum += c;
      }
      sh_prefix = (prefix << 8) | (unsigned int)d;
      sh_remaining = remaining - before;
      sh_countless = count_less + before;
    }
    __syncthreads();
    prefix = sh_prefix;
    remaining = sh_remaining;
    count_less = sh_countless;
    __syncthreads();
  }
  unsigned int vstar = prefix;
  unsigned int need_eq = NPTS_ - count_less;

  __shared__ unsigned int wtot_less[4], wtot_eq[4];
  unsigned int base_less = 0, base_eq = 0;
  int lane = tid & 63, wv = tid >> 6;
  int* selr = sel + (size_t)r * NPTS_;
  for (int base = 0; base < N; base += 256) {
    int i = base + tid;
    bool less = false, eq = false;
    if (i < N) {
      unsigned int v = __float_as_uint(fabsf(gt[i]));
      less = v < vstar;
      eq = v == vstar;
    }
    unsigned long long ml_ = __ballot(less);
    unsigned long long me_ = __ballot(eq);
    unsigned long long lanemask = (lane == 0) ? 0ull : ((~0ull) >> (64 - lane));
    unsigned int pl = __popcll(ml_ & lanemask);
    unsigned int pe = __popcll(me_ & lanemask);
    if (lane == 0) { wtot_less[wv] = (unsigned int)__popcll(ml_); wtot_eq[wv] = (unsigned int)__popcll(me_); }
    __syncthreads();
    unsigned int off_l = 0, off_e = 0, tot_l = 0, tot_e = 0;
#pragma unroll
    for (int w2 = 0; w2 < 4; ++w2) {
      unsigned int tl = wtot_less[w2], te = wtot_eq[w2];
      if (w2 < wv) { off_l += tl; off_e += te; }
      tot_l += tl;
      tot_e += te;
    }
    if (less) selr[base_less + off_l + pl] = i;
    if (eq) {
      unsigned int er = base_eq + off_e + pe;
      if (er < need_eq) selr[count_less + er] = i;
    }
    base_less += tot_l;
    base_eq += tot_e;
    __syncthreads();
  }
}

// ---------------- sample fine + coarse; write hi/lo bf16 splits ----------------
__global__ __launch_bounds__(256) void sample_kernel(const int* __restrict__ sel,
                                                     const float* __restrict__ bboxes,
                                                     const float* __restrict__ featT,
                                                     const float* __restrict__ coarseT,
                                                     __hip_bfloat16* __restrict__ Xh,
                                                     __hip_bfloat16* __restrict__ Xl,
                                                     __hip_bfloat16* __restrict__ Cth,
                                                     __hip_bfloat16* __restrict__ Ctl,
                                                     int Wlev, int Hlev) {
  int rp = blockIdx.x;
  int r = rp / NPTS_;
  int idx = sel[rp];
  int tid = threadIdx.x;

  float px = ((float)(idx % Wlev) + 0.5f) / (float)Wlev;
  float py = ((float)(idx / Wlev) + 0.5f) / (float)Hlev;
  float bx0 = bboxes[r * 4 + 0], by0 = bboxes[r * 4 + 1];
  float bw = __fsub_rn(bboxes[r * 4 + 2], bx0);
  float bh = __fsub_rn(bboxes[r * 4 + 3], by0);
  float cx = __fadd_rn(bx0, __fmul_rn(px, bw));
  float cy = __fadd_rn(by0, __fmul_rn(py, bh));

  {
    float gx = __fsub_rn(__fmul_rn(cx, 0.25f), 0.5f);
    float gy = __fsub_rn(__fmul_rn(cy, 0.25f), 0.5f);
    float fxf = floorf(gx), fyf = floorf(gy);
    float fx = __fsub_rn(gx, fxf), fy = __fsub_rn(gy, fyf);
    int x0 = (int)fxf, y0 = (int)fyf;
    float ofx = __fsub_rn(1.f, fx), ofy = __fsub_rn(1.f, fy);
    float w00 = __fmul_rn(ofx, ofy);
    float w10 = __fmul_rn(fx, ofy);
    float w01 = __fmul_rn(ofx, fy);
    float w11 = __fmul_rn(fx, fy);
    bool vx0 = (x0 >= 0) && (x0 < 256), vx1 = (x0 + 1 >= 0) && (x0 + 1 < 256);
    bool vy0 = (y0 >= 0) && (y0 < 256), vy1 = (y0 + 1 >= 0) && (y0 + 1 < 256);
    float W00 = (vx0 && vy0) ? w00 : 0.f;
    float W10 = (vx1 && vy0) ? w10 : 0.f;
    float W01 = (vx0 && vy1) ? w01 : 0.f;
    float W11 = (vx1 && vy1) ? w11 : 0.f;
    int x0c = min(max(x0, 0), 255), x1c = min(max(x0 + 1, 0), 255);
    int y0c = min(max(y0, 0), 255), y1c = min(max(y0 + 1, 0), 255);
    const float* p00 = featT + ((size_t)(y0c * 256 + x0c)) * 256;
    const float* p10 = featT + ((size_t)(y0c * 256 + x1c)) * 256;
    const float* p01 = featT + ((size_t)(y1c * 256 + x0c)) * 256;
    const float* p11 = featT + ((size_t)(y1c * 256 + x1c)) * 256;
    float acc = __fmul_rn(p00[tid], W00);
    acc = __fadd_rn(acc, __fmul_rn(p10[tid], W10));
    acc = __fadd_rn(acc, __fmul_rn(p01[tid], W01));
    acc = __fadd_rn(acc, __fmul_rn(p11[tid], W11));
    __hip_bfloat16 h = __float2bfloat16(acc);
    Xh[(size_t)rp * 256 + tid] = h;
    Xl[(size_t)rp * 256 + tid] = __float2bfloat16(acc - __bfloat162float(h));
  }

  if (tid < 96) {
    float acc = 0.f;
    if (tid < K_) {
      float gx = __fsub_rn(__fmul_rn(px, 7.f), 0.5f);
      float gy = __fsub_rn(__fmul_rn(py, 7.f), 0.5f);
      float fxf = floorf(gx), fyf = floorf(gy);
      float fx = __fsub_rn(gx, fxf), fy = __fsub_rn(gy, fyf);
      int x0 = (int)fxf, y0 = (int)fyf;
      float ofx = __fsub_rn(1.f, fx), ofy = __fsub_rn(1.f, fy);
      float w00 = __fmul_rn(ofx, ofy);
      float w10 = __fmul_rn(fx, ofy);
      float w01 = __fmul_rn(ofx, fy);
      float w11 = __fmul_rn(fx, fy);
      bool vx0 = (x0 >= 0) && (x0 < 7), vx1 = (x0 + 1 >= 0) && (x0 + 1 < 7);
      bool vy0 = (y0 >= 0) && (y0 < 7), vy1 = (y0 + 1 >= 0) && (y0 + 1 < 7);
      float W00 = (vx0 && vy0) ? w00 : 0.f;
      float W10 = (vx1 && vy0) ? w10 : 0.f;
      float W01 = (vx0 && vy1) ? w01 : 0.f;
      float W11 = (vx1 && vy1) ? w11 : 0.f;
      int x0c = min(max(x0, 0), 6), x1c = min(max(x0 + 1, 0), 6);
      int y0c = min(max(y0, 0), 6), y1c = min(max(y0 + 1, 0), 6);
      const float* cb = coarseT + (size_t)r * 49 * K_;
      acc = __fmul_rn(cb[(size_t)(y0c * 7 + x0c) * K_ + tid], W00);
      acc = __fadd_rn(acc, __fmul_rn(cb[(size_t)(y0c * 7 + x1c) * K_ + tid], W10));
      acc = __fadd_rn(acc, __fmul_rn(cb[(size_t)(y1c * 7 + x0c) * K_ + tid], W01));
      acc = __fadd_rn(acc, __fmul_rn(cb[(size_t)(y1c * 7 + x1c) * K_ + tid], W11));
    }
    __hip_bfloat16 h = __float2bfloat16(acc);
    Cth[(size_t)rp * 96 + tid] = h;
    Ctl[(size_t)rp * 96 + tid] = __float2bfloat16(acc - __bfloat162float(h));
  }
}

// ---------------- MFMA GEMM: out[m][o] = act(sum_k W[o][k]*A[m][k] + b[o]) ----------------
// TERMS=3: error-compensated Ah*Wh + Ah*Wl + Al*Wh (hi/lo split everywhere).
// TERMS=1: plain bf16 (step 3 only; its output never feeds top-k selection).
// A split: k<256 from Ah/Al [M][256]; k>=256 from Th/Tl [M][96] (cols 81..95 zero).
// Block 128x128, 4 waves of 64x64.
template <int TERMS, int RELU>
__global__ __launch_bounds__(256) void mfma_gemm_kernel(
    const __hip_bfloat16* __restrict__ Ah, const __hip_bfloat16* __restrict__ Al,
    const __hip_bfloat16* __restrict__ Th, const __hip_bfloat16* __restrict__ Tl,
    const __hip_bfloat16* __restrict__ Wh, const __hip_bfloat16* __restrict__ Wl,
    const float* __restrict__ bias,
    void* __restrict__ outH, void* __restrict__ outL) {
  constexpr int BUFSZ = (TERMS == 3) ? 32768 : 16384;
  __shared__ char lds[2 * BUFSZ];
  const int tid = threadIdx.x;
  const int lane = tid & 63;
  const int w = tid >> 6;
  const int m0 = blockIdx.x * 128;
  const int o0 = blockIdx.y * 128;
  const int wm = w >> 1, wn = w & 1;

  f32x4 acc[4][4];
#pragma unroll
  for (int i = 0; i < 4; ++i)
#pragma unroll
    for (int j = 0; j < 4; ++j) acc[i][j] = (f32x4){0.f, 0.f, 0.f, 0.f};

  const int srow0 = w * 16 + (lane >> 2);
  const int sp = lane & 3;
  constexpr int WOFF = (TERMS == 3) ? 16384 : 8192;

  auto stage = [&](int kt, int buf) {
    char* base = lds + buf * BUFSZ;
#pragma unroll
    for (int c = 0; c < 2; ++c) {
      const int row = c * 64 + srow0;
      const int s = sp ^ ((row >> 1) & 3);
      char* ldst = base + (c * 64 + w * 16) * 64;
      if (kt < 8) {
        size_t off = (((size_t)(m0 + row)) * 256 + (size_t)kt * 32 + (size_t)s * 8) * 2;
        GLDS16((const char*)Ah + off, ldst);
        if constexpr (TERMS == 3) GLDS16((const char*)Al + off, ldst + 8192);
      } else {
        size_t off = (((size_t)(m0 + row)) * 96 + (size_t)(kt - 8) * 32 + (size_t)s * 8) * 2;
        GLDS16((const char*)Th + off, ldst);
        if constexpr (TERMS == 3) GLDS16((const char*)Tl + off, ldst + 8192);
      }
      size_t woff = (((size_t)(o0 + row)) * 352 + (size_t)kt * 32 + (size_t)s * 8) * 2;
      GLDS16((const char*)Wh + woff, ldst + WOFF);
      if constexpr (TERMS == 3) GLDS16((const char*)Wl + woff, ldst + 24576);
    }
  };

  stage(0, 0);
  asm volatile("s_waitcnt vmcnt(0)" ::: "memory");
  __syncthreads();
  int cur = 0;
  for (int kt = 0; kt < 11; ++kt) {
    if (kt < 10) stage(kt + 1, cur ^ 1);
    const char* Atile_h = lds + cur * BUFSZ;
    const char* Atile_l = Atile_h + 8192;
    const char* Btile_h = Atile_h + WOFF;
    const char* Btile_l = Atile_h + 24576;
    short8 ah[4], al[4], bh[4], bl[4];
    const int g = lane >> 4;
#pragma unroll
    for (int i = 0; i < 4; ++i) {
      int rowA = wm * 64 + i * 16 + (lane & 15);
      int offA = rowA * 64 + ((g ^ ((rowA >> 1) & 3)) << 4);
      ah[i] = *(const short8*)(Atile_h + offA);
      if constexpr (TERMS == 3) al[i] = *(const short8*)(Atile_l + offA);
      int rowB = wn * 64 + i * 16 + (lane & 15);
      int offB = rowB * 64 + ((g ^ ((rowB >> 1) & 3)) << 4);
      bh[i] = *(const short8*)(Btile_h + offB);
      if constexpr (TERMS == 3) bl[i] = *(const short8*)(Btile_l + offB);
    }
#pragma unroll
    for (int i = 0; i < 4; ++i)
#pragma unroll
      for (int j = 0; j < 4; ++j) {
        acc[i][j] = __builtin_amdgcn_mfma_f32_16x16x32_bf16(ah[i], bh[j], acc[i][j], 0, 0, 0);
        if constexpr (TERMS == 3) {
          acc[i][j] = __builtin_amdgcn_mfma_f32_16x16x32_bf16(ah[i], bl[j], acc[i][j], 0, 0, 0);
          acc[i][j] = __builtin_amdgcn_mfma_f32_16x16x32_bf16(al[i], bh[j], acc[i][j], 0, 0, 0);
        }
      }
    asm volatile("s_waitcnt vmcnt(0)" ::: "memory");
    __syncthreads();
    cur ^= 1;
  }

  if (RELU) {
    __hip_bfloat16* oh = (__hip_bfloat16*)outH;
    __hip_bfloat16* ol = (__hip_bfloat16*)outL;
#pragma unroll
    for (int j = 0; j < 4; ++j) {
      int o = o0 + wn * 64 + j * 16 + (lane & 15);
      float bv = bias[o];
#pragma unroll
      for (int i = 0; i < 4; ++i) {
        int mbase = m0 + wm * 64 + i * 16 + (lane >> 4) * 4;
#pragma unroll
        for (int r = 0; r < 4; ++r) {
          float v = fmaxf(acc[i][j][r] + bv, 0.f);
          __hip_bfloat16 h = __float2bfloat16(v);
          size_t idx = (size_t)(mbase + r) * 256 + o;
          oh[idx] = h;
          if constexpr (TERMS == 3) ol[idx] = __float2bfloat16(v - __bfloat162float(h));
        }
      }
    }
  } else {
    float* op = (float*)outH;
#pragma unroll
    for (int j = 0; j < 4; ++j) {
      int o = o0 + wn * 64 + j * 16 + (lane & 15);
      float bv = bias[o];
#pragma unroll
      for (int i = 0; i < 4; ++i) {
        int mbase = m0 + wm * 64 + i * 16 + (lane >> 4) * 4;
#pragma unroll
        for (int r = 0; r < 4; ++r) {
          op[(size_t)(mbase + r) * 128 + o] = acc[i][j][r] + bv;
        }
      }
    }
  }
}

// ---------------- scatter head outputs into ml ----------------
__global__ void scatter_kernel(const float* __restrict__ PL, const int* __restrict__ sel,
                               float* __restrict__ ml, int Nlev) {
  int t = blockIdx.x * 256 + threadIdx.x;
  if (t >= R_ * NPTS_ * K_) return;
  int k = t % K_;
  int rp = t / K_;
  int i = sel[rp];
  int r = rp / NPTS_;
  ml[((size_t)r * K_ + k) * Nlev + i] = PL[(size_t)rp * 128 + k];
}

extern "C" void kernel_launch(void* const* d_in, const int* in_sizes, int n_in,
                              void* d_out, int out_size, void* d_ws, size_t ws_size,
                              hipStream_t stream) {
  (void)in_sizes; (void)n_in; (void)out_size; (void)ws_size;
  const float* feat = (const float*)d_in[0];
  const float* bboxes = (const float*)d_in[1];
  const int* labels = (const int*)d_in[2];
  const float* coarse = (const float*)d_in[3];
  const float* W1 = (const float*)d_in[4];
  const float* b1 = (const float*)d_in[5];
  const float* W2 = (const float*)d_in[6];
  const float* b2 = (const float*)d_in[7];
  const float* W3 = (const float*)d_in[8];
  const float* b3 = (const float*)d_in[9];
  const float* Wp = (const float*)d_in[10];
  const float* bp = (const float*)d_in[11];
  float* out = (float*)d_out;

  char* p = (char*)d_ws;
  auto alloc = [&](size_t bytes) { char* r = p; p += (bytes + 255) & ~(size_t)255; return r; };
  float* featT = (float*)alloc(16777216ull * 4);
  float* coarseT = (float*)alloc(254016ull * 4);
  float* ml14 = (float*)alloc(1016064ull * 4);
  float* ml28 = (float*)alloc(4064256ull * 4);
  float* ml56 = (float*)alloc(16257024ull * 4);
  float* PL = (float*)alloc(6422528ull * 4);
  int* sel = (int*)alloc(50176ull * 4);
  __hip_bfloat16* Xa_h = (__hip_bfloat16*)alloc(12845056ull * 2);
  __hip_bfloat16* Xa_l = (__hip_bfloat16*)alloc(12845056ull * 2);
  __hip_bfloat16* Xb_h = (__hip_bfloat16*)alloc(12845056ull * 2);
  __hip_bfloat16* Xb_l = (__hip_bfloat16*)alloc(12845056ull * 2);
  __hip_bfloat16* Ct_h = (__hip_bfloat16*)alloc(4816896ull * 2);
  __hip_bfloat16* Ct_l = (__hip_bfloat16*)alloc(4816896ull * 2);
  __hip_bfloat16* WH = (__hip_bfloat16*)alloc(315392ull * 2);
  __hip_bfloat16* WL = (__hip_bfloat16*)alloc(315392ull * 2);
  float* bp128 = (float*)alloc(128ull * 4);

  const int N = R_ * NPTS_;  // 50176
  const int B = R_ * K_;     // 5184

  transpose_feat_kernel<<<dim3(8, 8, 256), dim3(32, 8), 0, stream>>>(feat, featT);
  transpose_coarse_kernel<<<3969, 256, 0, stream>>>(coarse, coarseT);
  prep_weights_kernel<<<1233, 256, 0, stream>>>(W1, W2, W3, Wp, bp, WH, WL, bp128);

  const __hip_bfloat16* W1h = WH;
  const __hip_bfloat16* W2h = WH + 256 * 352;
  const __hip_bfloat16* W3h = WH + 512 * 352;
  const __hip_bfloat16* Wph = WH + 768 * 352;
  const __hip_bfloat16* W1l = WL;
  const __hip_bfloat16* W2l = WL + 256 * 352;
  const __hip_bfloat16* W3l = WL + 512 * 352;
  const __hip_bfloat16* Wpl = WL + 768 * 352;

  // step 0: 7 -> 14 (no refine)
  upsample2x_kernel<<<dim3(1, 4, B), dim3(64, 2), 0, stream>>>(coarse, ml14, 7, 7);

  // ---- step 1: 14 -> 28, refine ALL 784 points (exact 3-term head) ----
  upsample2x_kernel<<<dim3(1, 7, B), dim3(64, 2), 0, stream>>>(ml14, ml28, 14, 14);
  iota_kernel<<<196, 256, 0, stream>>>(sel);
  sample_kernel<<<N, 256, 0, stream>>>(sel, bboxes, featT, coarseT, Xa_h, Xa_l, Ct_h, Ct_l, 28, 28);
  mfma_gemm_kernel<3, 1><<<dim3(392, 2), 256, 0, stream>>>(Xa_h, Xa_l, Ct_h, Ct_l, W1h, W1l, b1, Xb_h, Xb_l);
  mfma_gemm_kernel<3, 1><<<dim3(392, 2), 256, 0, stream>>>(Xb_h, Xb_l, Ct_h, Ct_l, W2h, W2l, b2, Xa_h, Xa_l);
  mfma_gemm_kernel<3, 1><<<dim3(392, 2), 256, 0, stream>>>(Xa_h, Xa_l, Ct_h, Ct_l, W3h, W3l, b3, Xb_h, Xb_l);
  mfma_gemm_kernel<3, 0><<<dim3(392, 1), 256, 0, stream>>>(Xb_h, Xb_l, Ct_h, Ct_l, Wph, Wpl, bp128, PL, nullptr);
  scatter_kernel<<<15876, 256, 0, stream>>>(PL, sel, ml28, 784);

  // ---- step 2: 28 -> 56, refine top-784 of 3136 (exact 3-term head) ----
  upsample2x_kernel<<<dim3(1, 14, B), dim3(64, 2), 0, stream>>>(ml28, ml56, 28, 28);
  topk_kernel<<<R_, 256, 0, stream>>>(ml56, labels, 3136, sel);
  sample_kernel<<<N, 256, 0, stream>>>(sel, bboxes, featT, coarseT, Xa_h, Xa_l, Ct_h, Ct_l, 56, 56);
  mfma_gemm_kernel<3, 1><<<dim3(392, 2), 256, 0, stream>>>(Xa_h, Xa_l, Ct_h, Ct_l, W1h, W1l, b1, Xb_h, Xb_l);
  mfma_gemm_kernel<3, 1><<<dim3(392, 2), 256, 0, stream>>>(Xb_h, Xb_l, Ct_h, Ct_l, W2h, W2l, b2, Xa_h, Xa_l);
  mfma_gemm_kernel<3, 1><<<dim3(392, 2), 256, 0, stream>>>(Xa_h, Xa_l, Ct_h, Ct_l, W3h, W3l, b3, Xb_h, Xb_l);
  mfma_gemm_kernel<3, 0><<<dim3(392, 1), 256, 0, stream>>>(Xb_h, Xb_l, Ct_h, Ct_l, Wph, Wpl, bp128, PL, nullptr);
  scatter_kernel<<<15876, 256, 0, stream>>>(PL, sel, ml56, 3136);

  // ---- step 3: 56 -> 112 (into d_out), refine top-784 of 12544 (1-term bf16 head:
  //      its output feeds no selection, only final scattered values) ----
  upsample2x_kernel<<<dim3(1, 28, B), dim3(64, 2), 0, stream>>>(ml56, out, 56, 56);
  topk_kernel<<<R_, 256, 0, stream>>>(out, labels, 12544, sel);
  sample_kernel<<<N, 256, 0, stream>>>(sel, bboxes, featT, coarseT, Xa_h, Xa_l, Ct_h, Ct_l, 112, 112);
  mfma_gemm_kernel<1, 1><<<dim3(392, 2), 256, 0, stream>>>(Xa_h, nullptr, Ct_h, nullptr, W1h, nullptr, b1, Xb_h, nullptr);
  mfma_gemm_kernel<1, 1><<<dim3(392, 2), 256, 0, stream>>>(Xb_h, nullptr, Ct_h, nullptr, W2h, nullptr, b2, Xa_h, nullptr);
  mfma_gemm_kernel<1, 1><<<dim3(392, 2), 256, 0, stream>>>(Xa_h, nullptr, Ct_h, nullptr, W3h, nullptr, b3, Xb_h, nullptr);
  mfma_gemm_kernel<1, 0><<<dim3(392, 1), 256, 0, stream>>>(Xb_h, nullptr, Ct_h, nullptr, Wph, nullptr, bp128, PL, nullptr);
  scatter_kernel<<<15876, 256, 0, stream>>>(PL, sel, out, 12544);
}